// Round 1
// baseline (259.506 us; speedup 1.0000x reference)
//
#include <hip/hip_runtime.h>
#include <stdint.h>

// ---------------------------------------------------------------------------
// QUIK quantized linear, M=N=K=4096.
//   out[b,o] = (dot(x_q[b,:], w_q[o,:]) + bias[o]) * sa * sw
//              + (xmin + 4*sa) * wsum[b]            (B == out quirk: row index)
// Round 5: GEMM rewritten as 256x256 tile, 8 waves, BK=64 x2 sub-tiles/iter,
// double-buffered 128 KB LDS, counted vmcnt(4) pipeline (never drained to 0
// in the main loop), raw s_barrier, setprio around MFMA cluster.
// ---------------------------------------------------------------------------

using i32x4  = __attribute__((ext_vector_type(4))) int;
using i32x16 = __attribute__((ext_vector_type(16))) int;

#define TID ((int)threadIdx.x)

// ---------------- stats: 8192 blocks, 16 KB each, no atomics ---------------
__global__ __launch_bounds__(256) void k_stats(const float4* __restrict__ x,
                                               const float4* __restrict__ w,
                                               float* __restrict__ pmin,
                                               float* __restrict__ pmax,
                                               float* __restrict__ wsum) {
  const int blk = blockIdx.x;
  const bool isw = blk < 4096;
  const float4* src = isw ? (w + (size_t)blk * 1024)
                          : (x + (size_t)(blk - 4096) * 1024);
  float4 v0 = src[TID], v1 = src[256 + TID], v2 = src[512 + TID], v3 = src[768 + TID];
  float lmin = fminf(fminf(fminf(v0.x, v0.y), fminf(v0.z, v0.w)),
                     fminf(fminf(v1.x, v1.y), fminf(v1.z, v1.w)));
  lmin = fminf(lmin, fminf(fminf(fminf(v2.x, v2.y), fminf(v2.z, v2.w)),
                           fminf(fminf(v3.x, v3.y), fminf(v3.z, v3.w))));
  float lmax = fmaxf(fmaxf(fmaxf(v0.x, v0.y), fmaxf(v0.z, v0.w)),
                     fmaxf(fmaxf(v1.x, v1.y), fmaxf(v1.z, v1.w)));
  lmax = fmaxf(lmax, fmaxf(fmaxf(fmaxf(v2.x, v2.y), fmaxf(v2.z, v2.w)),
                           fmaxf(fmaxf(v3.x, v3.y), fmaxf(v3.z, v3.w))));
  float lsum = ((v0.x + v0.y) + (v0.z + v0.w)) + ((v1.x + v1.y) + (v1.z + v1.w)) +
               ((v2.x + v2.y) + (v2.z + v2.w)) + ((v3.x + v3.y) + (v3.z + v3.w));

#pragma unroll
  for (int d = 32; d > 0; d >>= 1) {
    lmin = fminf(lmin, __shfl_down(lmin, d));
    lmax = fmaxf(lmax, __shfl_down(lmax, d));
    lsum += __shfl_down(lsum, d);
  }
  __shared__ float smn[4], smx[4], ssm[4];
  const int wv = TID >> 6;
  if ((TID & 63) == 0) { smn[wv] = lmin; smx[wv] = lmax; ssm[wv] = lsum; }
  __syncthreads();
  if (TID == 0) {
    float mn = fminf(fminf(smn[0], smn[1]), fminf(smn[2], smn[3]));
    float mx = fmaxf(fmaxf(smx[0], smx[1]), fmaxf(smx[2], smx[3]));
    pmin[blk] = mn; pmax[blk] = mx;
    if (isw) wsum[blk] = (ssm[0] + ssm[1]) + (ssm[2] + ssm[3]);
  }
}

// Single block: reduce 8192 partials -> mmf = {xmin, xmax, wmin, wmax}.
__global__ __launch_bounds__(256) void k_final(const float* __restrict__ pmin,
                                               const float* __restrict__ pmax,
                                               float* __restrict__ mmf) {
  float wmn = 1e30f, wmx = -1e30f, xmn = 1e30f, xmx = -1e30f;
  for (int i = TID; i < 4096; i += 256) {
    wmn = fminf(wmn, pmin[i]);        wmx = fmaxf(wmx, pmax[i]);
    xmn = fminf(xmn, pmin[4096 + i]); xmx = fmaxf(xmx, pmax[4096 + i]);
  }
#pragma unroll
  for (int d = 32; d > 0; d >>= 1) {
    xmn = fminf(xmn, __shfl_down(xmn, d));
    xmx = fmaxf(xmx, __shfl_down(xmx, d));
    wmn = fminf(wmn, __shfl_down(wmn, d));
    wmx = fmaxf(wmx, __shfl_down(wmx, d));
  }
  __shared__ float s[4][4];
  const int wv = TID >> 6;
  if ((TID & 63) == 0) { s[wv][0] = xmn; s[wv][1] = xmx; s[wv][2] = wmn; s[wv][3] = wmx; }
  __syncthreads();
  if (TID == 0) {
    mmf[0] = fminf(fminf(s[0][0], s[1][0]), fminf(s[2][0], s[3][0]));
    mmf[1] = fmaxf(fmaxf(s[0][1], s[1][1]), fmaxf(s[2][1], s[3][1]));
    mmf[2] = fminf(fminf(s[0][2], s[1][2]), fminf(s[2][2], s[3][2]));
    mmf[3] = fmaxf(fmaxf(s[0][3], s[1][3]), fmaxf(s[2][3], s[3][3]));
  }
}

// ---------------- quant: bit-exact np fp32 op replication -> int8 ----------
__device__ __forceinline__ int q1i(float t, float zero, float scale) {
  float v = (t - zero) / scale - 4.0f;   // IEEE div, matches np
  v = fminf(3.0f, fmaxf(-4.0f, v));
  return (int)v;                         // trunc toward zero == astype(int32)
}

__device__ __forceinline__ unsigned pack4(float4 v, float zero, float scale) {
  return (q1i(v.x, zero, scale) & 255) | ((q1i(v.y, zero, scale) & 255) << 8) |
         ((q1i(v.z, zero, scale) & 255) << 16) | ((q1i(v.w, zero, scale) & 255) << 24);
}

__global__ __launch_bounds__(256) void k_quant(const float4* __restrict__ x,
                                               const float4* __restrict__ w,
                                               uint4* __restrict__ Xq,
                                               uint4* __restrict__ Wq,
                                               const float* __restrict__ mmf) {
  bool isx = (blockIdx.x < 4096);
  int row = isx ? blockIdx.x : (blockIdx.x - 4096);
  const float4* in = (isx ? x : w) + (size_t)row * 1024 + TID * 4;
  uint4* outq = (isx ? Xq : Wq) + (size_t)row * 256 + TID;
  float zero = isx ? mmf[0] : mmf[2];
  float scale = ((isx ? mmf[1] : mmf[3]) - zero) * 0.125f;  // (max-min)/8 exact
  float4 a = in[0], b = in[1], c = in[2], d = in[3];
  uint4 o;
  o.x = pack4(a, zero, scale);
  o.y = pack4(b, zero, scale);
  o.z = pack4(c, zero, scale);
  o.w = pack4(d, zero, scale);
  *outq = o;
}

__device__ __forceinline__ void gload_lds16(const char* g, char* l) {
  __builtin_amdgcn_global_load_lds(
      (__attribute__((address_space(1))) void*)(g),
      (__attribute__((address_space(3))) void*)(l), 16, 0, 0);
}

// ---------------- GEMM: block 256x256, 8 waves, counted-vmcnt pipeline -----
// LDS map (128 KB): A at [side*32768 + kk*16384 + row*64 + pc*16], side=dbuf,
// kk = K-subtile (BK=64) within iteration; B same + 65536. Swizzle: physical
// chunk pc of row r holds logical chunk pc ^ (r&3) (pre-swizzled global src,
// linear LDS dest -- required by global_load_lds).
// Wave w: rows wm=(w>>2)*128, cols wn=(w&3)*64; 4x2 of mfma_i32_32x32x32_i8.
// A-frag (HW-verified r3): lane holds A[row=wm+i*32+(lane&31)][k=kt*32+(lane>>5)*16+j].
// C/D (verified m74/m101): col = lane&31, row = (reg&3)+8*(reg>>2)+4*(lane>>5).
//
// Schedule per iteration (2 BK=64 tiles), 4 phases ph=(kk,kt):
//   ds_read 6xb128 (phase frags, side cur)
//   stage 2x global_load_lds (slice: ph0=A-kk0, ph1=B-kk0, ph2=A-kk1, ph3=B-kk1
//          of tiles 2it+2/2it+3 -> side nxt)
//   [ph1,ph3] s_waitcnt vmcnt(4)   // drains 4-oldest: exactly the slices the
//                                  // reads 2 phases later need; never 0
//   s_barrier ; lgkmcnt(0) ; setprio(1) ; 8 MFMA ; setprio(0) ; s_barrier
__global__ __launch_bounds__(512, 2) void k_gemm(const char* __restrict__ Xq,
                                                 const char* __restrict__ Wq,
                                                 const float* __restrict__ bias,
                                                 const float* __restrict__ wsum,
                                                 const float* __restrict__ mmf,
                                                 float* __restrict__ out) {
  __shared__ __align__(16) char LDS[131072];

  const int tid = TID;
  const int lane = tid & 63, wave = tid >> 6;
  const int c5 = lane & 31, h = lane >> 5;
  const int wm = (wave >> 2) * 128, wn = (wave & 3) * 64;

  // Bijective XCD swizzle: 256 blocks = 8 XCDs x 32 contiguous.
  const int bid = (int)blockIdx.x;
  const int swz = (bid & 7) * 32 + (bid >> 3);
  const int bx = swz & 15, by = swz >> 4;
  const int brow = by * 256, bcol = bx * 256;

  // Staging: thread t -> row t>>2 of a 128-row slice, physical chunk t&3,
  // logical chunk (t&3)^((t>>2)&3). LDS dest = slice_base + t*16 (linear).
  const int srow = tid >> 2;
  const int lcg = (tid & 3) ^ (srow & 3);
  const char* gA = Xq + (size_t)(brow + srow) * 4096 + lcg * 16;
  const char* gB = Wq + (size_t)(bcol + srow) * 4096 + lcg * 16;

  i32x16 acc[4][2];
#pragma unroll
  for (int i = 0; i < 4; ++i)
#pragma unroll
    for (int j = 0; j < 2; ++j)
#pragma unroll
      for (int e = 0; e < 16; ++e) acc[i][j][e] = 0;

  // Prologue: stage tiles 0,1 into side 0, issue order == phase slice order.
#pragma unroll
  for (int s = 0; s < 8; ++s) {
    const int kk = s >> 2, arr = (s >> 1) & 1, sh = s & 1;
    const char* gs = arr ? gB : gA;
    gload_lds16(gs + (size_t)kk * 64 + (size_t)sh * (128 * 4096),
                LDS + arr * 65536 + kk * 16384 + sh * 8192 + tid * 16);
  }
  asm volatile("s_waitcnt vmcnt(4)" ::: "memory");  // kk0 slices landed
  __builtin_amdgcn_s_barrier();

#pragma unroll 2
  for (int it = 0; it < 31; ++it) {
    const int cur = it & 1, nxt = cur ^ 1;
    const int curA = cur * 32768, curB = 65536 + cur * 32768;
    const int nxtA = nxt * 32768, nxtB = 65536 + nxt * 32768;
    const size_t kOff = (size_t)(2 * it + 2) * 64;  // tiles being staged
#pragma unroll
    for (int ph = 0; ph < 4; ++ph) {
      const int kk = ph >> 1, ktl = ph & 1;
      const int pco = ((ktl * 2 + h) ^ (c5 & 3)) * 16;
      const int ab = curA + kk * 16384 + pco;
      const int bb = curB + kk * 16384 + pco;
      i32x4 af0 = *(const i32x4*)(LDS + ab + (wm + c5) * 64);
      i32x4 af1 = *(const i32x4*)(LDS + ab + (wm + 32 + c5) * 64);
      i32x4 af2 = *(const i32x4*)(LDS + ab + (wm + 64 + c5) * 64);
      i32x4 af3 = *(const i32x4*)(LDS + ab + (wm + 96 + c5) * 64);
      i32x4 bf0 = *(const i32x4*)(LDS + bb + (wn + c5) * 64);
      i32x4 bf1 = *(const i32x4*)(LDS + bb + (wn + 32 + c5) * 64);
      // Stage one slice-pair (A or B, sub-tile kk) of the next iteration.
      const char* gs = ktl ? gB : gA;
      char* ld = LDS + (ktl ? nxtB : nxtA) + kk * 16384 + tid * 16;
      gload_lds16(gs + kOff + (size_t)kk * 64, ld);
      gload_lds16(gs + kOff + (size_t)kk * 64 + (size_t)(128 * 4096), ld + 8192);
      if (ktl) asm volatile("s_waitcnt vmcnt(4)" ::: "memory");
      __builtin_amdgcn_s_barrier();
      asm volatile("s_waitcnt lgkmcnt(0)" ::: "memory");
      __builtin_amdgcn_sched_barrier(0);
      __builtin_amdgcn_s_setprio(1);
      acc[0][0] = __builtin_amdgcn_mfma_i32_32x32x32_i8(af0, bf0, acc[0][0], 0, 0, 0);
      acc[0][1] = __builtin_amdgcn_mfma_i32_32x32x32_i8(af0, bf1, acc[0][1], 0, 0, 0);
      acc[1][0] = __builtin_amdgcn_mfma_i32_32x32x32_i8(af1, bf0, acc[1][0], 0, 0, 0);
      acc[1][1] = __builtin_amdgcn_mfma_i32_32x32x32_i8(af1, bf1, acc[1][1], 0, 0, 0);
      acc[2][0] = __builtin_amdgcn_mfma_i32_32x32x32_i8(af2, bf0, acc[2][0], 0, 0, 0);
      acc[2][1] = __builtin_amdgcn_mfma_i32_32x32x32_i8(af2, bf1, acc[2][1], 0, 0, 0);
      acc[3][0] = __builtin_amdgcn_mfma_i32_32x32x32_i8(af3, bf0, acc[3][0], 0, 0, 0);
      acc[3][1] = __builtin_amdgcn_mfma_i32_32x32x32_i8(af3, bf1, acc[3][1], 0, 0, 0);
      __builtin_amdgcn_s_setprio(0);
      __builtin_amdgcn_s_barrier();
    }
  }

  // Tail: tiles 62,63 sit in side 1; nothing left in flight to hide.
  asm volatile("s_waitcnt vmcnt(0)" ::: "memory");
  __builtin_amdgcn_s_barrier();
#pragma unroll
  for (int ph = 0; ph < 4; ++ph) {
    const int kk = ph >> 1, ktl = ph & 1;
    const int pco = ((ktl * 2 + h) ^ (c5 & 3)) * 16;
    const int ab = 32768 + kk * 16384 + pco;
    const int bb = 98304 + kk * 16384 + pco;
    i32x4 af0 = *(const i32x4*)(LDS + ab + (wm + c5) * 64);
    i32x4 af1 = *(const i32x4*)(LDS + ab + (wm + 32 + c5) * 64);
    i32x4 af2 = *(const i32x4*)(LDS + ab + (wm + 64 + c5) * 64);
    i32x4 af3 = *(const i32x4*)(LDS + ab + (wm + 96 + c5) * 64);
    i32x4 bf0 = *(const i32x4*)(LDS + bb + (wn + c5) * 64);
    i32x4 bf1 = *(const i32x4*)(LDS + bb + (wn + 32 + c5) * 64);
    acc[0][0] = __builtin_amdgcn_mfma_i32_32x32x32_i8(af0, bf0, acc[0][0], 0, 0, 0);
    acc[0][1] = __builtin_amdgcn_mfma_i32_32x32x32_i8(af0, bf1, acc[0][1], 0, 0, 0);
    acc[1][0] = __builtin_amdgcn_mfma_i32_32x32x32_i8(af1, bf0, acc[1][0], 0, 0, 0);
    acc[1][1] = __builtin_amdgcn_mfma_i32_32x32x32_i8(af1, bf1, acc[1][1], 0, 0, 0);
    acc[2][0] = __builtin_amdgcn_mfma_i32_32x32x32_i8(af2, bf0, acc[2][0], 0, 0, 0);
    acc[2][1] = __builtin_amdgcn_mfma_i32_32x32x32_i8(af2, bf1, acc[2][1], 0, 0, 0);
    acc[3][0] = __builtin_amdgcn_mfma_i32_32x32x32_i8(af3, bf0, acc[3][0], 0, 0, 0);
    acc[3][1] = __builtin_amdgcn_mfma_i32_32x32x32_i8(af3, bf1, acc[3][1], 0, 0, 0);
  }

  // Epilogue (ref op order preserved bit-exactly).
  float sa = (mmf[1] - mmf[0]) * 0.125f;
  float sw = (mmf[3] - mmf[2]) * 0.125f;
  float mid = mmf[0] + 4.0f * sa;

  const int col0 = bcol + wn + c5;
  const float b0 = bias[col0], b1 = bias[col0 + 32];
#pragma unroll
  for (int i = 0; i < 4; ++i) {
    const int rbase = brow + wm + i * 32 + 4 * h;
#pragma unroll
    for (int g = 0; g < 4; ++g) {
#pragma unroll
      for (int q = 0; q < 4; ++q) {
        const int row = rbase + 8 * g + q;
        const float shift = mid * wsum[row];
        float* po = out + (size_t)row * 4096 + col0;
        po[0]  = ((float)acc[i][0][g * 4 + q] + b0) * sa * sw + shift;
        po[32] = ((float)acc[i][1][g * 4 + q] + b1) * sa * sw + shift;
      }
    }
  }
}

extern "C" void kernel_launch(void* const* d_in, const int* in_sizes, int n_in,
                              void* d_out, int out_size, void* d_ws, size_t ws_size,
                              hipStream_t stream) {
  (void)in_sizes; (void)n_in; (void)out_size; (void)ws_size;
  const float* x = (const float*)d_in[0];
  const float* w = (const float*)d_in[1];
  const float* bias = (const float*)d_in[2];
  float* out = (float*)d_out;

  char* ws = (char*)d_ws;
  float* mmf = (float*)ws;                             // 4 floats: xmin,xmax,wmin,wmax
  float* wsum = (float*)(ws + 1024);                   // 4096 floats
  float* pmin = (float*)(ws + 32768);                  // 8192 floats
  float* pmax = (float*)(ws + 65536);                  // 8192 floats
  char* Xq = ws + 131072;                              // 4096x4096 i8 (16.8 MB)
  char* Wq = ws + 131072 + (size_t)16777216;           // 4096x4096 i8 (16.8 MB)

  k_stats<<<8192, 256, 0, stream>>>((const float4*)x, (const float4*)w, pmin, pmax, wsum);
  k_final<<<1, 256, 0, stream>>>(pmin, pmax, mmf);
  k_quant<<<8192, 256, 0, stream>>>((const float4*)x, (const float4*)w,
                                    (uint4*)Xq, (uint4*)Wq, mmf);
  k_gemm<<<256, 512, 0, stream>>>(Xq, Wq, bias, wsum, mmf, out);
}

// Round 2
// 247.684 us; speedup vs baseline: 1.0477x; 1.0477x over previous
//
#include <hip/hip_runtime.h>
#include <stdint.h>

// ---------------------------------------------------------------------------
// QUIK quantized linear, M=N=K=4096.
//   out[b,o] = (dot(x_q[b,:], w_q[o,:]) + bias[o]) * sa * sw
//              + (xmin + 4*sa) * wsum[b]            (B == out quirk: row index)
// Round 6: same 256x256 / 8-wave / counted-vmcnt(4) pipeline as round 5, but
// LDS swizzle fixed: XOR with (row>>1)&3 instead of row&3. With 64-B rows the
// bank-group is 4*(row&1) + (chunk ^ swz); XOR-ing bits [2:1] of the row makes
// (row&1, swz) enumerate all 8 groups -> full 8-way spread (round-5's row&3
// only ever hit 4 groups -> 8-way conflicts, SQ_LDS_BANK_CONFLICT 3x).
// ---------------------------------------------------------------------------

using i32x4  = __attribute__((ext_vector_type(4))) int;
using i32x16 = __attribute__((ext_vector_type(16))) int;

#define TID ((int)threadIdx.x)

// ---------------- stats: 8192 blocks, 16 KB each, no atomics ---------------
__global__ __launch_bounds__(256) void k_stats(const float4* __restrict__ x,
                                               const float4* __restrict__ w,
                                               float* __restrict__ pmin,
                                               float* __restrict__ pmax,
                                               float* __restrict__ wsum) {
  const int blk = blockIdx.x;
  const bool isw = blk < 4096;
  const float4* src = isw ? (w + (size_t)blk * 1024)
                          : (x + (size_t)(blk - 4096) * 1024);
  float4 v0 = src[TID], v1 = src[256 + TID], v2 = src[512 + TID], v3 = src[768 + TID];
  float lmin = fminf(fminf(fminf(v0.x, v0.y), fminf(v0.z, v0.w)),
                     fminf(fminf(v1.x, v1.y), fminf(v1.z, v1.w)));
  lmin = fminf(lmin, fminf(fminf(fminf(v2.x, v2.y), fminf(v2.z, v2.w)),
                           fminf(fminf(v3.x, v3.y), fminf(v3.z, v3.w))));
  float lmax = fmaxf(fmaxf(fmaxf(v0.x, v0.y), fmaxf(v0.z, v0.w)),
                     fmaxf(fmaxf(v1.x, v1.y), fmaxf(v1.z, v1.w)));
  lmax = fmaxf(lmax, fmaxf(fmaxf(fmaxf(v2.x, v2.y), fmaxf(v2.z, v2.w)),
                           fmaxf(fmaxf(v3.x, v3.y), fmaxf(v3.z, v3.w))));
  float lsum = ((v0.x + v0.y) + (v0.z + v0.w)) + ((v1.x + v1.y) + (v1.z + v1.w)) +
               ((v2.x + v2.y) + (v2.z + v2.w)) + ((v3.x + v3.y) + (v3.z + v3.w));

#pragma unroll
  for (int d = 32; d > 0; d >>= 1) {
    lmin = fminf(lmin, __shfl_down(lmin, d));
    lmax = fmaxf(lmax, __shfl_down(lmax, d));
    lsum += __shfl_down(lsum, d);
  }
  __shared__ float smn[4], smx[4], ssm[4];
  const int wv = TID >> 6;
  if ((TID & 63) == 0) { smn[wv] = lmin; smx[wv] = lmax; ssm[wv] = lsum; }
  __syncthreads();
  if (TID == 0) {
    float mn = fminf(fminf(smn[0], smn[1]), fminf(smn[2], smn[3]));
    float mx = fmaxf(fmaxf(smx[0], smx[1]), fmaxf(smx[2], smx[3]));
    pmin[blk] = mn; pmax[blk] = mx;
    if (isw) wsum[blk] = (ssm[0] + ssm[1]) + (ssm[2] + ssm[3]);
  }
}

// Single block: reduce 8192 partials -> mmf = {xmin, xmax, wmin, wmax}.
__global__ __launch_bounds__(256) void k_final(const float* __restrict__ pmin,
                                               const float* __restrict__ pmax,
                                               float* __restrict__ mmf) {
  float wmn = 1e30f, wmx = -1e30f, xmn = 1e30f, xmx = -1e30f;
  for (int i = TID; i < 4096; i += 256) {
    wmn = fminf(wmn, pmin[i]);        wmx = fmaxf(wmx, pmax[i]);
    xmn = fminf(xmn, pmin[4096 + i]); xmx = fmaxf(xmx, pmax[4096 + i]);
  }
#pragma unroll
  for (int d = 32; d > 0; d >>= 1) {
    xmn = fminf(xmn, __shfl_down(xmn, d));
    xmx = fmaxf(xmx, __shfl_down(xmx, d));
    wmn = fminf(wmn, __shfl_down(wmn, d));
    wmx = fmaxf(wmx, __shfl_down(wmx, d));
  }
  __shared__ float s[4][4];
  const int wv = TID >> 6;
  if ((TID & 63) == 0) { s[wv][0] = xmn; s[wv][1] = xmx; s[wv][2] = wmn; s[wv][3] = wmx; }
  __syncthreads();
  if (TID == 0) {
    mmf[0] = fminf(fminf(s[0][0], s[1][0]), fminf(s[2][0], s[3][0]));
    mmf[1] = fmaxf(fmaxf(s[0][1], s[1][1]), fmaxf(s[2][1], s[3][1]));
    mmf[2] = fminf(fminf(s[0][2], s[1][2]), fminf(s[2][2], s[3][2]));
    mmf[3] = fmaxf(fmaxf(s[0][3], s[1][3]), fmaxf(s[2][3], s[3][3]));
  }
}

// ---------------- quant: bit-exact np fp32 op replication -> int8 ----------
__device__ __forceinline__ int q1i(float t, float zero, float scale) {
  float v = (t - zero) / scale - 4.0f;   // IEEE div, matches np
  v = fminf(3.0f, fmaxf(-4.0f, v));
  return (int)v;                         // trunc toward zero == astype(int32)
}

__device__ __forceinline__ unsigned pack4(float4 v, float zero, float scale) {
  return (q1i(v.x, zero, scale) & 255) | ((q1i(v.y, zero, scale) & 255) << 8) |
         ((q1i(v.z, zero, scale) & 255) << 16) | ((q1i(v.w, zero, scale) & 255) << 24);
}

__global__ __launch_bounds__(256) void k_quant(const float4* __restrict__ x,
                                               const float4* __restrict__ w,
                                               uint4* __restrict__ Xq,
                                               uint4* __restrict__ Wq,
                                               const float* __restrict__ mmf) {
  bool isx = (blockIdx.x < 4096);
  int row = isx ? blockIdx.x : (blockIdx.x - 4096);
  const float4* in = (isx ? x : w) + (size_t)row * 1024 + TID * 4;
  uint4* outq = (isx ? Xq : Wq) + (size_t)row * 256 + TID;
  float zero = isx ? mmf[0] : mmf[2];
  float scale = ((isx ? mmf[1] : mmf[3]) - zero) * 0.125f;  // (max-min)/8 exact
  float4 a = in[0], b = in[1], c = in[2], d = in[3];
  uint4 o;
  o.x = pack4(a, zero, scale);
  o.y = pack4(b, zero, scale);
  o.z = pack4(c, zero, scale);
  o.w = pack4(d, zero, scale);
  *outq = o;
}

__device__ __forceinline__ void gload_lds16(const char* g, char* l) {
  __builtin_amdgcn_global_load_lds(
      (__attribute__((address_space(1))) void*)(g),
      (__attribute__((address_space(3))) void*)(l), 16, 0, 0);
}

// ---------------- GEMM: block 256x256, 8 waves, counted-vmcnt pipeline -----
// LDS map (128 KB): A at [side*32768 + kk*16384 + row*64 + pc*16], side=dbuf,
// kk = K-subtile (BK=64) within iteration; B same + 65536.
// Swizzle: physical chunk pc of row r holds logical chunk pc ^ ((r>>1)&3)
// (pre-swizzled global src, linear LDS dest -- required by global_load_lds).
// Bank-group of a 16-B slot = (addr>>4)&7 = 4*(r&1) + (pc); with this XOR the
// map c5 -> group is a bijection over c5&7 -> conflict-minimal (4 lanes/group
// per 32-lane half), matching the measured-good 128-B-row layout.
// Wave w: rows wm=(w>>2)*128, cols wn=(w&3)*64; 4x2 of mfma_i32_32x32x32_i8.
// A-frag (HW-verified r3): lane holds A[row=wm+i*32+(lane&31)][k=kt*32+(lane>>5)*16+j].
// C/D (verified m74/m101): col = lane&31, row = (reg&3)+8*(reg>>2)+4*(lane>>5).
//
// Schedule per iteration (2 BK=64 tiles), 4 phases ph=(kk,kt):
//   ds_read 6xb128 (phase frags, side cur)
//   stage 2x global_load_lds (slice: ph0=A-kk0, ph1=B-kk0, ph2=A-kk1, ph3=B-kk1
//          of tiles 2it+2/2it+3 -> side nxt)
//   [ph1,ph3] s_waitcnt vmcnt(4)   // drains 4-oldest: exactly the slices the
//                                  // reads 2 phases later need; never 0
//   s_barrier ; lgkmcnt(0) ; setprio(1) ; 8 MFMA ; setprio(0) ; s_barrier
__global__ __launch_bounds__(512, 2) void k_gemm(const char* __restrict__ Xq,
                                                 const char* __restrict__ Wq,
                                                 const float* __restrict__ bias,
                                                 const float* __restrict__ wsum,
                                                 const float* __restrict__ mmf,
                                                 float* __restrict__ out) {
  __shared__ __align__(16) char LDS[131072];

  const int tid = TID;
  const int lane = tid & 63, wave = tid >> 6;
  const int c5 = lane & 31, h = lane >> 5;
  const int wm = (wave >> 2) * 128, wn = (wave & 3) * 64;

  // Bijective XCD swizzle: 256 blocks = 8 XCDs x 32 contiguous.
  const int bid = (int)blockIdx.x;
  const int swz = (bid & 7) * 32 + (bid >> 3);
  const int bx = swz & 15, by = swz >> 4;
  const int brow = by * 256, bcol = bx * 256;

  // Staging: thread t -> row t>>2 of a 128-row slice, physical chunk t&3,
  // logical chunk (t&3)^((t>>3)&3). LDS dest = slice_base + t*16 (linear).
  const int srow = tid >> 2;
  const int lcg = (tid & 3) ^ ((tid >> 3) & 3);
  const char* gA = Xq + (size_t)(brow + srow) * 4096 + lcg * 16;
  const char* gB = Wq + (size_t)(bcol + srow) * 4096 + lcg * 16;

  // Read-side physical chunk for logical chunk (ktl*2+h): XOR with (row>>1)&3;
  // all fragment rows are c5 mod 64-aligned offsets -> (row>>1)&3 == (c5>>1)&3.
  const int rsw = (c5 >> 1) & 3;

  i32x16 acc[4][2];
#pragma unroll
  for (int i = 0; i < 4; ++i)
#pragma unroll
    for (int j = 0; j < 2; ++j)
#pragma unroll
      for (int e = 0; e < 16; ++e) acc[i][j][e] = 0;

  // Prologue: stage tiles 0,1 into side 0, issue order == phase slice order.
#pragma unroll
  for (int s = 0; s < 8; ++s) {
    const int kk = s >> 2, arr = (s >> 1) & 1, sh = s & 1;
    const char* gs = arr ? gB : gA;
    gload_lds16(gs + (size_t)kk * 64 + (size_t)sh * (128 * 4096),
                LDS + arr * 65536 + kk * 16384 + sh * 8192 + tid * 16);
  }
  asm volatile("s_waitcnt vmcnt(4)" ::: "memory");  // kk0 slices landed
  __builtin_amdgcn_s_barrier();

#pragma unroll 2
  for (int it = 0; it < 31; ++it) {
    const int cur = it & 1, nxt = cur ^ 1;
    const int curA = cur * 32768, curB = 65536 + cur * 32768;
    const int nxtA = nxt * 32768, nxtB = 65536 + nxt * 32768;
    const size_t kOff = (size_t)(2 * it + 2) * 64;  // tiles being staged
#pragma unroll
    for (int ph = 0; ph < 4; ++ph) {
      const int kk = ph >> 1, ktl = ph & 1;
      const int pco = ((ktl * 2 + h) ^ rsw) * 16;
      const int ab = curA + kk * 16384 + pco;
      const int bb = curB + kk * 16384 + pco;
      i32x4 af0 = *(const i32x4*)(LDS + ab + (wm + c5) * 64);
      i32x4 af1 = *(const i32x4*)(LDS + ab + (wm + 32 + c5) * 64);
      i32x4 af2 = *(const i32x4*)(LDS + ab + (wm + 64 + c5) * 64);
      i32x4 af3 = *(const i32x4*)(LDS + ab + (wm + 96 + c5) * 64);
      i32x4 bf0 = *(const i32x4*)(LDS + bb + (wn + c5) * 64);
      i32x4 bf1 = *(const i32x4*)(LDS + bb + (wn + 32 + c5) * 64);
      // Stage one slice-pair (A or B, sub-tile kk) of the next iteration.
      const char* gs = ktl ? gB : gA;
      char* ld = LDS + (ktl ? nxtB : nxtA) + kk * 16384 + tid * 16;
      gload_lds16(gs + kOff + (size_t)kk * 64, ld);
      gload_lds16(gs + kOff + (size_t)kk * 64 + (size_t)(128 * 4096), ld + 8192);
      if (ktl) asm volatile("s_waitcnt vmcnt(4)" ::: "memory");
      __builtin_amdgcn_s_barrier();
      asm volatile("s_waitcnt lgkmcnt(0)" ::: "memory");
      __builtin_amdgcn_sched_barrier(0);
      __builtin_amdgcn_s_setprio(1);
      acc[0][0] = __builtin_amdgcn_mfma_i32_32x32x32_i8(af0, bf0, acc[0][0], 0, 0, 0);
      acc[0][1] = __builtin_amdgcn_mfma_i32_32x32x32_i8(af0, bf1, acc[0][1], 0, 0, 0);
      acc[1][0] = __builtin_amdgcn_mfma_i32_32x32x32_i8(af1, bf0, acc[1][0], 0, 0, 0);
      acc[1][1] = __builtin_amdgcn_mfma_i32_32x32x32_i8(af1, bf1, acc[1][1], 0, 0, 0);
      acc[2][0] = __builtin_amdgcn_mfma_i32_32x32x32_i8(af2, bf0, acc[2][0], 0, 0, 0);
      acc[2][1] = __builtin_amdgcn_mfma_i32_32x32x32_i8(af2, bf1, acc[2][1], 0, 0, 0);
      acc[3][0] = __builtin_amdgcn_mfma_i32_32x32x32_i8(af3, bf0, acc[3][0], 0, 0, 0);
      acc[3][1] = __builtin_amdgcn_mfma_i32_32x32x32_i8(af3, bf1, acc[3][1], 0, 0, 0);
      __builtin_amdgcn_s_setprio(0);
      __builtin_amdgcn_s_barrier();
    }
  }

  // Tail: tiles 62,63 sit in side 1; nothing left in flight to hide.
  asm volatile("s_waitcnt vmcnt(0)" ::: "memory");
  __builtin_amdgcn_s_barrier();
#pragma unroll
  for (int ph = 0; ph < 4; ++ph) {
    const int kk = ph >> 1, ktl = ph & 1;
    const int pco = ((ktl * 2 + h) ^ rsw) * 16;
    const int ab = 32768 + kk * 16384 + pco;
    const int bb = 98304 + kk * 16384 + pco;
    i32x4 af0 = *(const i32x4*)(LDS + ab + (wm + c5) * 64);
    i32x4 af1 = *(const i32x4*)(LDS + ab + (wm + 32 + c5) * 64);
    i32x4 af2 = *(const i32x4*)(LDS + ab + (wm + 64 + c5) * 64);
    i32x4 af3 = *(const i32x4*)(LDS + ab + (wm + 96 + c5) * 64);
    i32x4 bf0 = *(const i32x4*)(LDS + bb + (wn + c5) * 64);
    i32x4 bf1 = *(const i32x4*)(LDS + bb + (wn + 32 + c5) * 64);
    acc[0][0] = __builtin_amdgcn_mfma_i32_32x32x32_i8(af0, bf0, acc[0][0], 0, 0, 0);
    acc[0][1] = __builtin_amdgcn_mfma_i32_32x32x32_i8(af0, bf1, acc[0][1], 0, 0, 0);
    acc[1][0] = __builtin_amdgcn_mfma_i32_32x32x32_i8(af1, bf0, acc[1][0], 0, 0, 0);
    acc[1][1] = __builtin_amdgcn_mfma_i32_32x32x32_i8(af1, bf1, acc[1][1], 0, 0, 0);
    acc[2][0] = __builtin_amdgcn_mfma_i32_32x32x32_i8(af2, bf0, acc[2][0], 0, 0, 0);
    acc[2][1] = __builtin_amdgcn_mfma_i32_32x32x32_i8(af2, bf1, acc[2][1], 0, 0, 0);
    acc[3][0] = __builtin_amdgcn_mfma_i32_32x32x32_i8(af3, bf0, acc[3][0], 0, 0, 0);
    acc[3][1] = __builtin_amdgcn_mfma_i32_32x32x32_i8(af3, bf1, acc[3][1], 0, 0, 0);
  }

  // Epilogue (ref op order preserved bit-exactly).
  float sa = (mmf[1] - mmf[0]) * 0.125f;
  float sw = (mmf[3] - mmf[2]) * 0.125f;
  float mid = mmf[0] + 4.0f * sa;

  const int col0 = bcol + wn + c5;
  const float b0 = bias[col0], b1 = bias[col0 + 32];
#pragma unroll
  for (int i = 0; i < 4; ++i) {
    const int rbase = brow + wm + i * 32 + 4 * h;
#pragma unroll
    for (int g = 0; g < 4; ++g) {
#pragma unroll
      for (int q = 0; q < 4; ++q) {
        const int row = rbase + 8 * g + q;
        const float shift = mid * wsum[row];
        float* po = out + (size_t)row * 4096 + col0;
        po[0]  = ((float)acc[i][0][g * 4 + q] + b0) * sa * sw + shift;
        po[32] = ((float)acc[i][1][g * 4 + q] + b1) * sa * sw + shift;
      }
    }
  }
}

extern "C" void kernel_launch(void* const* d_in, const int* in_sizes, int n_in,
                              void* d_out, int out_size, void* d_ws, size_t ws_size,
                              hipStream_t stream) {
  (void)in_sizes; (void)n_in; (void)out_size; (void)ws_size;
  const float* x = (const float*)d_in[0];
  const float* w = (const float*)d_in[1];
  const float* bias = (const float*)d_in[2];
  float* out = (float*)d_out;

  char* ws = (char*)d_ws;
  float* mmf = (float*)ws;                             // 4 floats: xmin,xmax,wmin,wmax
  float* wsum = (float*)(ws + 1024);                   // 4096 floats
  float* pmin = (float*)(ws + 32768);                  // 8192 floats
  float* pmax = (float*)(ws + 65536);                  // 8192 floats
  char* Xq = ws + 131072;                              // 4096x4096 i8 (16.8 MB)
  char* Wq = ws + 131072 + (size_t)16777216;           // 4096x4096 i8 (16.8 MB)

  k_stats<<<8192, 256, 0, stream>>>((const float4*)x, (const float4*)w, pmin, pmax, wsum);
  k_final<<<1, 256, 0, stream>>>(pmin, pmax, mmf);
  k_quant<<<8192, 256, 0, stream>>>((const float4*)x, (const float4*)w,
                                    (uint4*)Xq, (uint4*)Wq, mmf);
  k_gemm<<<256, 512, 0, stream>>>(Xq, Wq, bias, wsum, mmf, out);
}